// Round 4
// baseline (875.110 us; speedup 1.0000x reference)
//
#include <hip/hip_runtime.h>
#include <hip/hip_bf16.h>
#include <hip/hip_fp16.h>
#include <math.h>

#define NN 50000
#define NE 400000
#define INDIM 128
#define HID 64
#define HC 256
#define NL 6
#define ED 16
#define SCAN_B 256
#define SCAN_NB ((NN + SCAN_B - 1)/SCAN_B)   // 196

typedef __attribute__((ext_vector_type(8))) short short8;
typedef __attribute__((ext_vector_type(4))) float f32x4;

static __device__ __forceinline__ float4 ld4(const float* p){ return *(const float4*)p; }
static __device__ __forceinline__ unsigned short f2b(float x){
  __hip_bfloat16 h = __float2bfloat16(x);
  return *(unsigned short*)&h;
}
static __device__ __forceinline__ unsigned short f2h(float x){
  __half h = __float2half(x);
  return *(unsigned short*)&h;
}
static __device__ __forceinline__ float h2f(unsigned short u){
  __half h = *(__half*)&u;
  return __half2float(h);
}

// ---------------- prep: bf16 weights + Wl/Wr fusion + ep_table ----------------
__global__ void prep_kernel(const float* __restrict__ inW, const float* __restrict__ Wl,
                            const float* __restrict__ Wr, const float* __restrict__ bl,
                            const float* __restrict__ br, const float* __restrict__ etab,
                            const float* __restrict__ We,
                            unsigned short* __restrict__ inW_bf,
                            unsigned short* __restrict__ Wlr,
                            float* __restrict__ blr, float* __restrict__ ep){
  int i = blockIdx.x*blockDim.x + threadIdx.x;
  if (i < HID*INDIM) inW_bf[i] = f2b(inW[i]);
  if (i < NL*512){
    int l = i / 512, c = i % 512;
    blr[i] = (c < HC) ? bl[l*HC + c] : br[l*HC + (c-HC)];
  }
  if (i < NL*3*HC){
    int l  = i / (3*HC);
    int a  = (i / HC) % 3;
    int hc = i % HC;
    const float* wrow = We + ((size_t)l*HC + hc)*ED;
    const float* erow = etab + a*ED;
    float s = 0.f;
    #pragma unroll
    for (int k=0;k<ED;k++) s += erow[k]*wrow[k];
    ep[i] = s;
  }
  int tot = NL*512*HID;
  for (int j = i; j < tot; j += gridDim.x*blockDim.x){
    int l = j / (512*HID);
    int c = (j / HID) % 512;
    int k = j % HID;
    float v = (c < HC) ? Wl[((size_t)l*HC + c)*HID + k]
                       : Wr[((size_t)l*HC + (c-HC))*HID + k];
    Wlr[j] = f2b(v);
  }
}

// ---------------- CSR build ----------------
__global__ void deg_kernel(const int* __restrict__ dst, int* __restrict__ deg){
  int e = blockIdx.x*blockDim.x + threadIdx.x;
  if (e < NE) atomicAdd(&deg[dst[e]], 1);
}

__global__ void scanA_kernel(const int* __restrict__ deg, int* __restrict__ bsum){
  int t = threadIdx.x;
  int i = blockIdx.x*SCAN_B + t;
  int v = (i < NN) ? deg[i] : 0;
  #pragma unroll
  for (int o=1;o<64;o<<=1) v += __shfl_xor(v,o);
  __shared__ int ws[4];
  if ((t&63)==0) ws[t>>6] = v;
  __syncthreads();
  if (t==0) bsum[blockIdx.x] = ws[0]+ws[1]+ws[2]+ws[3];
}

__global__ void scanB_kernel(int* __restrict__ bsum){
  __shared__ int sh[256];
  int t = threadIdx.x;
  int v = (t < SCAN_NB) ? bsum[t] : 0;
  sh[t] = v;
  __syncthreads();
  for (int o=1;o<256;o<<=1){
    int u = (t>=o)?sh[t-o]:0;
    __syncthreads();
    sh[t]+=u;
    __syncthreads();
  }
  int excl = (t==0)?0:sh[t-1];
  if (t < SCAN_NB) bsum[t] = excl;
}

__global__ void scanC_kernel(const int* __restrict__ deg, const int* __restrict__ bsum,
                             int* __restrict__ rowp){
  int t = threadIdx.x, b = blockIdx.x;
  int i = b*SCAN_B + t;
  int v = (i<NN)?deg[i]:0;
  __shared__ int sh[256];
  sh[t]=v;
  __syncthreads();
  for (int o=1;o<256;o<<=1){
    int u=(t>=o)?sh[t-o]:0;
    __syncthreads();
    sh[t]+=u;
    __syncthreads();
  }
  if (i < NN) rowp[i] = bsum[b] + sh[t] - v;
  if (i == 0) rowp[NN] = NE;
}

// scatter packed (src | attr<<16); consumes deg as a countdown counter
__global__ void scatter_kernel(const int* __restrict__ src, const int* __restrict__ dst,
                               const int* __restrict__ attr, const int* __restrict__ rowp,
                               int* __restrict__ deg, int* __restrict__ csrp){
  int e = blockIdx.x*blockDim.x + threadIdx.x;
  if (e >= NE) return;
  int d = dst[e];
  int pos = rowp[d] + atomicSub(&deg[d], 1) - 1;
  csrp[pos] = src[e] | (attr[e] << 16);
}

// ---------------- input GEMM: h = x @ inW.T + b ----------------
__global__ __launch_bounds__(256) void gemm_in_kernel(
    const float* __restrict__ X, const unsigned short* __restrict__ Wbf,
    const float* __restrict__ bias, float* __restrict__ hout, unsigned short* __restrict__ hbf)
{
  int wid = threadIdx.x >> 6, lane = threadIdx.x & 63;
  int row0 = blockIdx.x*128 + wid*32;
  int lr = lane & 15, lk = lane >> 4;
  short8 a[2][4];
  #pragma unroll
  for (int rt=0; rt<2; rt++){
    int r = row0 + rt*16 + lr; if (r >= NN) r = NN-1;
    const float* rp = X + (size_t)r*INDIM;
    #pragma unroll
    for (int ks=0; ks<4; ks++){
      const float* p = rp + ks*32 + lk*8;
      float4 u = ld4(p), v = ld4(p+4);
      short8 t;
      t[0]=(short)f2b(u.x); t[1]=(short)f2b(u.y); t[2]=(short)f2b(u.z); t[3]=(short)f2b(u.w);
      t[4]=(short)f2b(v.x); t[5]=(short)f2b(v.y); t[6]=(short)f2b(v.z); t[7]=(short)f2b(v.w);
      a[rt][ks] = t;
    }
  }
  f32x4 acc[2][4] = {};
  #pragma unroll
  for (int ct=0; ct<4; ct++){
    int c = ct*16 + lr;
    #pragma unroll
    for (int ks=0; ks<4; ks++){
      short8 b = *(const short8*)&Wbf[(size_t)c*INDIM + ks*32 + lk*8];
      #pragma unroll
      for (int rt=0; rt<2; rt++)
        acc[rt][ct] = __builtin_amdgcn_mfma_f32_16x16x32_bf16(a[rt][ks], b, acc[rt][ct], 0,0,0);
    }
  }
  #pragma unroll
  for (int rt=0; rt<2; rt++)
    #pragma unroll
    for (int ct=0; ct<4; ct++){
      int c = ct*16 + lr;
      float bv = bias[c];
      #pragma unroll
      for (int q=0;q<4;q++){
        int r = row0 + rt*16 + lk*4 + q;
        if (r < NN){
          float v = acc[rt][ct][q] + bv;
          hout[(size_t)r*HID + c] = v;
          hbf[(size_t)r*HID + c] = f2b(v);
        }
      }
    }
}

// ---------------- layer GEMM: xlr = h_bf @ Wlr.T + blr ([NN][512] fp16) ----------------
__global__ __launch_bounds__(256) void gemm_lr_kernel(
    const unsigned short* __restrict__ Abf, const unsigned short* __restrict__ Wbf,
    const float* __restrict__ bias, unsigned short* __restrict__ out)
{
  int wid = threadIdx.x >> 6, lane = threadIdx.x & 63;
  int row0 = blockIdx.x*128 + wid*32;
  int col0 = blockIdx.y*64;
  int lr = lane & 15, lk = lane >> 4;
  short8 a[2][2];
  #pragma unroll
  for (int rt=0; rt<2; rt++){
    int r = row0 + rt*16 + lr; if (r >= NN) r = NN-1;
    #pragma unroll
    for (int ks=0; ks<2; ks++)
      a[rt][ks] = *(const short8*)&Abf[(size_t)r*HID + ks*32 + lk*8];
  }
  f32x4 acc[2][4] = {};
  #pragma unroll
  for (int ct=0; ct<4; ct++){
    int c = col0 + ct*16 + lr;
    #pragma unroll
    for (int ks=0; ks<2; ks++){
      short8 b = *(const short8*)&Wbf[(size_t)c*HID + ks*32 + lk*8];
      #pragma unroll
      for (int rt=0; rt<2; rt++)
        acc[rt][ct] = __builtin_amdgcn_mfma_f32_16x16x32_bf16(a[rt][ks], b, acc[rt][ct], 0,0,0);
    }
  }
  #pragma unroll
  for (int rt=0; rt<2; rt++)
    #pragma unroll
    for (int ct=0; ct<4; ct++){
      int c = col0 + ct*16 + lr;
      float bv = bias[c];
      #pragma unroll
      for (int q=0;q<4;q++){
        int r = row0 + rt*16 + lk*4 + q;
        if (r < NN) out[(size_t)r*512 + c] = f2h(acc[rt][ct][q] + bv);
      }
    }
}

// ---------------- fused GATv2 aggregation + head-mean + LN + residual + relu ----------------
__global__ __launch_bounds__(256) void agg_kernel(
    const unsigned short* __restrict__ xlr,
    const int* __restrict__ rowp, const int* __restrict__ csrp,
    const float* __restrict__ ep_l, const float* __restrict__ att_l,
    const float* __restrict__ bias_l, const float* __restrict__ g_l, const float* __restrict__ b_l,
    const float* __restrict__ h_in, float* __restrict__ h_out, unsigned short* __restrict__ hbf,
    int use_res, int do_relu)
{
  int d = (blockIdx.x << 2) | (threadIdx.x >> 6);
  int lane = threadIdx.x & 63;
  if (d >= NN) return;
  int cb = lane << 2;

  ushort4 xr4 = *(const ushort4*)(xlr + ((size_t)d << 9) + 256 + cb);
  float xr0 = h2f(xr4.x), xr1 = h2f(xr4.y), xr2 = h2f(xr4.z), xr3 = h2f(xr4.w);
  float4 e0 = ld4(ep_l + cb);
  float4 e1 = ld4(ep_l + HC + cb);
  float4 e2 = ld4(ep_l + 2*HC + cb);
  float4 av = ld4(att_l + cb);
  float4 av2 = {0.2f*av.x, 0.2f*av.y, 0.2f*av.z, 0.2f*av.w};

  float den = 0.f;
  float ax=0.f, ay=0.f, az=0.f, aw=0.f;

  auto body = [&](ushort4 u, int a){
    float4 ev = (a==0) ? e0 : ((a==1) ? e1 : e2);
    float x0 = h2f(u.x), x1 = h2f(u.y), x2 = h2f(u.z), x3 = h2f(u.w);
    float m0 = x0 + xr0 + ev.x;
    float m1 = x1 + xr1 + ev.y;
    float m2 = x2 + xr2 + ev.z;
    float m3 = x3 + xr3 + ev.w;
    float part =      m0 * (m0 > 0.f ? av.x : av2.x);
    part = fmaf(m1, (m1 > 0.f ? av.y : av2.y), part);
    part = fmaf(m2, (m2 > 0.f ? av.z : av2.z), part);
    part = fmaf(m3, (m3 > 0.f ? av.w : av2.w), part);
    part += __shfl_xor(part, 1);
    part += __shfl_xor(part, 2);
    part += __shfl_xor(part, 4);
    part += __shfl_xor(part, 8);
    float p = __expf(part);      // logits are O(0.2): softmax shift-invariant, no overflow
    den += p;
    ax = fmaf(p, x0, ax);
    ay = fmaf(p, x1, ay);
    az = fmaf(p, x2, az);
    aw = fmaf(p, x3, aw);
  };

  int beg = rowp[d], stop = rowp[d+1];
  int i = beg;
  for (; i + 4 <= stop; i += 4){
    int p0 = csrp[i], p1 = csrp[i+1], p2 = csrp[i+2], p3 = csrp[i+3];
    ushort4 u0 = *(const ushort4*)(xlr + ((size_t)(p0 & 0xFFFF) << 9) + cb);
    ushort4 u1 = *(const ushort4*)(xlr + ((size_t)(p1 & 0xFFFF) << 9) + cb);
    ushort4 u2 = *(const ushort4*)(xlr + ((size_t)(p2 & 0xFFFF) << 9) + cb);
    ushort4 u3 = *(const ushort4*)(xlr + ((size_t)(p3 & 0xFFFF) << 9) + cb);
    body(u0, p0 >> 16);
    body(u1, p1 >> 16);
    body(u2, p2 >> 16);
    body(u3, p3 >> 16);
  }
  if (i + 2 <= stop){
    int p0 = csrp[i], p1 = csrp[i+1];
    ushort4 u0 = *(const ushort4*)(xlr + ((size_t)(p0 & 0xFFFF) << 9) + cb);
    ushort4 u1 = *(const ushort4*)(xlr + ((size_t)(p1 & 0xFFFF) << 9) + cb);
    body(u0, p0 >> 16);
    body(u1, p1 >> 16);
    i += 2;
  }
  if (i < stop){
    int p0 = csrp[i];
    ushort4 u0 = *(const ushort4*)(xlr + ((size_t)(p0 & 0xFFFF) << 9) + cb);
    body(u0, p0 >> 16);
  }

  float inv = (den > 0.f) ? 1.f/den : 0.f;
  ax *= inv; ay *= inv; az *= inv; aw *= inv;

  ax += __shfl_xor(ax,16); ay += __shfl_xor(ay,16); az += __shfl_xor(az,16); aw += __shfl_xor(aw,16);
  ax += __shfl_xor(ax,32); ay += __shfl_xor(ay,32); az += __shfl_xor(az,32); aw += __shfl_xor(aw,32);

  int cc = (lane & 15) << 2;
  float4 bv = ld4(bias_l + cc);
  float h0 = ax*0.25f + bv.x;
  float h1 = ay*0.25f + bv.y;
  float h2 = az*0.25f + bv.z;
  float h3 = aw*0.25f + bv.w;

  float s1 = h0+h1+h2+h3;
  float s2 = h0*h0 + h1*h1 + h2*h2 + h3*h3;
  s1 += __shfl_xor(s1,1); s2 += __shfl_xor(s2,1);
  s1 += __shfl_xor(s1,2); s2 += __shfl_xor(s2,2);
  s1 += __shfl_xor(s1,4); s2 += __shfl_xor(s2,4);
  s1 += __shfl_xor(s1,8); s2 += __shfl_xor(s2,8);
  float mu  = s1 * (1.f/64.f);
  float var = fmaxf(s2*(1.f/64.f) - mu*mu, 0.f);
  float rstd = rsqrtf(var + 1e-5f);
  float4 gv  = ld4(g_l + cc);
  float4 bbv = ld4(b_l + cc);
  float r0 = (h0-mu)*rstd*gv.x + bbv.x;
  float r1 = (h1-mu)*rstd*gv.y + bbv.y;
  float r2 = (h2-mu)*rstd*gv.z + bbv.z;
  float r3 = (h3-mu)*rstd*gv.w + bbv.w;
  if (use_res){
    float4 hv = ld4(h_in + (size_t)d*HID + cc);
    r0 += hv.x; r1 += hv.y; r2 += hv.z; r3 += hv.w;
  }
  if (do_relu){
    r0 = fmaxf(r0, 0.f); r1 = fmaxf(r1, 0.f);
    r2 = fmaxf(r2, 0.f); r3 = fmaxf(r3, 0.f);
  }
  if (lane < 16){
    float4 o = {r0, r1, r2, r3};
    *(float4*)(h_out + (size_t)d*HID + cc) = o;
    ushort4 ob = {f2b(r0), f2b(r1), f2b(r2), f2b(r3)};
    *(ushort4*)(hbf + (size_t)d*HID + cc) = ob;
  }
}

// ---------------- launch ----------------
extern "C" void kernel_launch(void* const* d_in, const int* in_sizes, int n_in,
                              void* d_out, int out_size, void* d_ws, size_t ws_size,
                              hipStream_t stream){
  const float* x    = (const float*)d_in[0];
  const int*   ei   = (const int*)d_in[1];
  const int*   ea   = (const int*)d_in[2];
  const float* inW  = (const float*)d_in[3];
  const float* inb  = (const float*)d_in[4];
  const float* etab = (const float*)d_in[5];
  const float* Wl   = (const float*)d_in[6];
  const float* bl   = (const float*)d_in[7];
  const float* Wr   = (const float*)d_in[8];
  const float* br   = (const float*)d_in[9];
  const float* We   = (const float*)d_in[10];
  const float* att  = (const float*)d_in[11];
  const float* ob   = (const float*)d_in[12];
  const float* lg   = (const float*)d_in[13];
  const float* lb   = (const float*)d_in[14];

  char* w = (char*)d_ws;
  size_t off = 0;
  auto alloc = [&](size_t bytes)->char*{
    char* p = w + off;
    off = (off + bytes + 255) & ~(size_t)255;
    return p;
  };
  float* hA    = (float*)alloc((size_t)NN*HID*4);
  float* hB    = (float*)alloc((size_t)NN*HID*4);
  unsigned short* hbf = (unsigned short*)alloc((size_t)NN*HID*2);
  unsigned short* xlr = (unsigned short*)alloc((size_t)NN*512*2);
  unsigned short* inW_bf = (unsigned short*)alloc((size_t)HID*INDIM*2);
  unsigned short* Wlr    = (unsigned short*)alloc((size_t)NL*512*HID*2);
  float* blr   = (float*)alloc((size_t)NL*512*4);
  float* ep    = (float*)alloc((size_t)NL*3*HC*4);
  int*   deg   = (int*)alloc((size_t)NN*4);
  int*   bsum  = (int*)alloc((size_t)SCAN_NB*4);
  int*   rowp  = (int*)alloc((size_t)(NN+1)*4);
  int*   csrp  = (int*)alloc((size_t)NE*4);

  hipMemsetAsync(deg, 0, (size_t)NN*4, stream);

  const int* srcp = ei;
  const int* dstp = ei + NE;
  deg_kernel<<<dim3((NE+255)/256), dim3(256), 0, stream>>>(dstp, deg);
  scanA_kernel<<<dim3(SCAN_NB), dim3(256), 0, stream>>>(deg, bsum);
  scanB_kernel<<<dim3(1), dim3(256), 0, stream>>>(bsum);
  scanC_kernel<<<dim3(SCAN_NB), dim3(256), 0, stream>>>(deg, bsum, rowp);
  scatter_kernel<<<dim3((NE+255)/256), dim3(256), 0, stream>>>(srcp, dstp, ea, rowp, deg, csrp);
  prep_kernel<<<dim3(64), dim3(256), 0, stream>>>(inW, Wl, Wr, bl, br, etab, We, inW_bf, Wlr, blr, ep);

  const int MB = (NN + 127)/128;   // 391
  gemm_in_kernel<<<dim3(MB), dim3(256), 0, stream>>>(x, inW_bf, inb, hA, hbf);

  float* hcur = hA; float* hnext = hB;
  for (int l=0; l<NL; l++){
    gemm_lr_kernel<<<dim3(MB,8), dim3(256), 0, stream>>>(
        hbf, Wlr + (size_t)l*512*HID, blr + (size_t)l*512, xlr);
    float* hout = (l == NL-1) ? (float*)d_out : hnext;
    agg_kernel<<<dim3((NN+3)/4), dim3(256), 0, stream>>>(
        xlr, rowp, csrp,
        ep + (size_t)l*3*HC, att + (size_t)l*HC,
        ob + (size_t)l*HID, lg + (size_t)l*HID, lb + (size_t)l*HID,
        hcur, hout, hbf, (l >= NL/2) ? 1 : 0, (l < NL-1) ? 1 : 0);
    float* t = hcur; hcur = hnext; hnext = t;
  }
}

// Round 5
// 599.477 us; speedup vs baseline: 1.4598x; 1.4598x over previous
//
#include <hip/hip_runtime.h>
#include <hip/hip_bf16.h>
#include <hip/hip_fp16.h>
#include <math.h>

#define NN 50000
#define NE 400000
#define INDIM 128
#define HID 64
#define HC 256
#define NL 6
#define ED 16
#define SCAN_B 256
#define SCAN_NB ((NN + SCAN_B - 1)/SCAN_B)   // 196

typedef __attribute__((ext_vector_type(8))) short short8;
typedef __attribute__((ext_vector_type(4))) float f32x4;

static __device__ __forceinline__ float4 ld4(const float* p){ return *(const float4*)p; }
static __device__ __forceinline__ unsigned short f2b(float x){
  __hip_bfloat16 h = __float2bfloat16(x);
  return *(unsigned short*)&h;
}
static __device__ __forceinline__ unsigned short f2h(float x){
  __half h = __float2half(x);
  return *(unsigned short*)&h;
}
static __device__ __forceinline__ float h2f(unsigned short u){
  __half h = *(__half*)&u;
  return __half2float(h);
}

// ---------------- prep: bf16 weights + Wl/Wr fusion + ep_table ----------------
__global__ void prep_kernel(const float* __restrict__ inW, const float* __restrict__ Wl,
                            const float* __restrict__ Wr, const float* __restrict__ bl,
                            const float* __restrict__ br, const float* __restrict__ etab,
                            const float* __restrict__ We,
                            unsigned short* __restrict__ inW_bf,
                            unsigned short* __restrict__ Wlr,
                            float* __restrict__ blr, float* __restrict__ ep){
  int i = blockIdx.x*blockDim.x + threadIdx.x;
  if (i < HID*INDIM) inW_bf[i] = f2b(inW[i]);
  if (i < NL*512){
    int l = i / 512, c = i % 512;
    blr[i] = (c < HC) ? bl[l*HC + c] : br[l*HC + (c-HC)];
  }
  if (i < NL*3*HC){
    int l  = i / (3*HC);
    int a  = (i / HC) % 3;
    int hc = i % HC;
    const float* wrow = We + ((size_t)l*HC + hc)*ED;
    const float* erow = etab + a*ED;
    float s = 0.f;
    #pragma unroll
    for (int k=0;k<ED;k++) s += erow[k]*wrow[k];
    ep[i] = s;
  }
  int tot = NL*512*HID;
  for (int j = i; j < tot; j += gridDim.x*blockDim.x){
    int l = j / (512*HID);
    int c = (j / HID) % 512;
    int k = j % HID;
    float v = (c < HC) ? Wl[((size_t)l*HC + c)*HID + k]
                       : Wr[((size_t)l*HC + (c-HC))*HID + k];
    Wlr[j] = f2b(v);
  }
}

// ---------------- CSR build ----------------
__global__ void deg_kernel(const int* __restrict__ dst, int* __restrict__ deg){
  int e = blockIdx.x*blockDim.x + threadIdx.x;
  if (e < NE) atomicAdd(&deg[dst[e]], 1);
}

__global__ void scanA_kernel(const int* __restrict__ deg, int* __restrict__ bsum){
  int t = threadIdx.x;
  int i = blockIdx.x*SCAN_B + t;
  int v = (i < NN) ? deg[i] : 0;
  #pragma unroll
  for (int o=1;o<64;o<<=1) v += __shfl_xor(v,o);
  __shared__ int ws[4];
  if ((t&63)==0) ws[t>>6] = v;
  __syncthreads();
  if (t==0) bsum[blockIdx.x] = ws[0]+ws[1]+ws[2]+ws[3];
}

__global__ void scanB_kernel(int* __restrict__ bsum){
  __shared__ int sh[256];
  int t = threadIdx.x;
  int v = (t < SCAN_NB) ? bsum[t] : 0;
  sh[t] = v;
  __syncthreads();
  for (int o=1;o<256;o<<=1){
    int u = (t>=o)?sh[t-o]:0;
    __syncthreads();
    sh[t]+=u;
    __syncthreads();
  }
  int excl = (t==0)?0:sh[t-1];
  if (t < SCAN_NB) bsum[t] = excl;
}

__global__ void scanC_kernel(const int* __restrict__ deg, const int* __restrict__ bsum,
                             int* __restrict__ rowp){
  int t = threadIdx.x, b = blockIdx.x;
  int i = b*SCAN_B + t;
  int v = (i<NN)?deg[i]:0;
  __shared__ int sh[256];
  sh[t]=v;
  __syncthreads();
  for (int o=1;o<256;o<<=1){
    int u=(t>=o)?sh[t-o]:0;
    __syncthreads();
    sh[t]+=u;
    __syncthreads();
  }
  if (i < NN) rowp[i] = bsum[b] + sh[t] - v;
  if (i == 0) rowp[NN] = NE;
}

// scatter packed (src | attr<<16); consumes deg as a countdown counter
__global__ void scatter_kernel(const int* __restrict__ src, const int* __restrict__ dst,
                               const int* __restrict__ attr, const int* __restrict__ rowp,
                               int* __restrict__ deg, int* __restrict__ csrp){
  int e = blockIdx.x*blockDim.x + threadIdx.x;
  if (e >= NE) return;
  int d = dst[e];
  int pos = rowp[d] + atomicSub(&deg[d], 1) - 1;
  csrp[pos] = src[e] | (attr[e] << 16);
}

// ---------------- input GEMM: h = x @ inW.T + b ----------------
__global__ __launch_bounds__(256) void gemm_in_kernel(
    const float* __restrict__ X, const unsigned short* __restrict__ Wbf,
    const float* __restrict__ bias, float* __restrict__ hout, unsigned short* __restrict__ hbf)
{
  int wid = threadIdx.x >> 6, lane = threadIdx.x & 63;
  int row0 = blockIdx.x*128 + wid*32;
  int lr = lane & 15, lk = lane >> 4;
  short8 a[2][4];
  #pragma unroll
  for (int rt=0; rt<2; rt++){
    int r = row0 + rt*16 + lr; if (r >= NN) r = NN-1;
    const float* rp = X + (size_t)r*INDIM;
    #pragma unroll
    for (int ks=0; ks<4; ks++){
      const float* p = rp + ks*32 + lk*8;
      float4 u = ld4(p), v = ld4(p+4);
      short8 t;
      t[0]=(short)f2b(u.x); t[1]=(short)f2b(u.y); t[2]=(short)f2b(u.z); t[3]=(short)f2b(u.w);
      t[4]=(short)f2b(v.x); t[5]=(short)f2b(v.y); t[6]=(short)f2b(v.z); t[7]=(short)f2b(v.w);
      a[rt][ks] = t;
    }
  }
  f32x4 acc[2][4] = {};
  #pragma unroll
  for (int ct=0; ct<4; ct++){
    int c = ct*16 + lr;
    #pragma unroll
    for (int ks=0; ks<4; ks++){
      short8 b = *(const short8*)&Wbf[(size_t)c*INDIM + ks*32 + lk*8];
      #pragma unroll
      for (int rt=0; rt<2; rt++)
        acc[rt][ct] = __builtin_amdgcn_mfma_f32_16x16x32_bf16(a[rt][ks], b, acc[rt][ct], 0,0,0);
    }
  }
  #pragma unroll
  for (int rt=0; rt<2; rt++)
    #pragma unroll
    for (int ct=0; ct<4; ct++){
      int c = ct*16 + lr;
      float bv = bias[c];
      #pragma unroll
      for (int q=0;q<4;q++){
        int r = row0 + rt*16 + lk*4 + q;
        if (r < NN){
          float v = acc[rt][ct][q] + bv;
          hout[(size_t)r*HID + c] = v;
          hbf[(size_t)r*HID + c] = f2b(v);
        }
      }
    }
}

// ---------------- layer GEMM: xlr = h_bf @ Wlr.T + blr ([NN][512] fp16) ----------------
__global__ __launch_bounds__(256) void gemm_lr_kernel(
    const unsigned short* __restrict__ Abf, const unsigned short* __restrict__ Wbf,
    const float* __restrict__ bias, unsigned short* __restrict__ out)
{
  int wid = threadIdx.x >> 6, lane = threadIdx.x & 63;
  int row0 = blockIdx.x*128 + wid*32;
  int col0 = blockIdx.y*64;
  int lr = lane & 15, lk = lane >> 4;
  short8 a[2][2];
  #pragma unroll
  for (int rt=0; rt<2; rt++){
    int r = row0 + rt*16 + lr; if (r >= NN) r = NN-1;
    #pragma unroll
    for (int ks=0; ks<2; ks++)
      a[rt][ks] = *(const short8*)&Abf[(size_t)r*HID + ks*32 + lk*8];
  }
  f32x4 acc[2][4] = {};
  #pragma unroll
  for (int ct=0; ct<4; ct++){
    int c = col0 + ct*16 + lr;
    #pragma unroll
    for (int ks=0; ks<2; ks++){
      short8 b = *(const short8*)&Wbf[(size_t)c*HID + ks*32 + lk*8];
      #pragma unroll
      for (int rt=0; rt<2; rt++)
        acc[rt][ct] = __builtin_amdgcn_mfma_f32_16x16x32_bf16(a[rt][ks], b, acc[rt][ct], 0,0,0);
    }
  }
  #pragma unroll
  for (int rt=0; rt<2; rt++)
    #pragma unroll
    for (int ct=0; ct<4; ct++){
      int c = col0 + ct*16 + lr;
      float bv = bias[c];
      #pragma unroll
      for (int q=0;q<4;q++){
        int r = row0 + rt*16 + lk*4 + q;
        if (r < NN) out[(size_t)r*512 + c] = f2h(acc[rt][ct][q] + bv);
      }
    }
}

// ---------------- fused GATv2 aggregation + head-mean + LN + residual + relu ----------------
// one wave per dst node; lane holds 4 channels of [H=4][C=64]; xlr fp16 [NN][512]
// round-3 structure: 2-wide unroll, per-edge ep table load (L1-resident 3 KB)
__global__ __launch_bounds__(256) void agg_kernel(
    const unsigned short* __restrict__ xlr,
    const int* __restrict__ rowp, const int* __restrict__ csrp,
    const float* __restrict__ ep_l, const float* __restrict__ att_l,
    const float* __restrict__ bias_l, const float* __restrict__ g_l, const float* __restrict__ b_l,
    const float* __restrict__ h_in, float* __restrict__ h_out, unsigned short* __restrict__ hbf,
    int use_res, int do_relu)
{
  int d = (blockIdx.x << 2) | (threadIdx.x >> 6);
  int lane = threadIdx.x & 63;
  if (d >= NN) return;
  int cb = lane << 2;

  ushort4 xr4 = *(const ushort4*)(xlr + ((size_t)d << 9) + 256 + cb);
  float xr0 = h2f(xr4.x), xr1 = h2f(xr4.y), xr2 = h2f(xr4.z), xr3 = h2f(xr4.w);
  float4 av = ld4(att_l + cb);
  float4 av2 = {0.2f*av.x, 0.2f*av.y, 0.2f*av.z, 0.2f*av.w};

  float den = 0.f;
  float ax=0.f, ay=0.f, az=0.f, aw=0.f;

  auto body = [&](ushort4 u, float4 ev){
    float x0 = h2f(u.x), x1 = h2f(u.y), x2 = h2f(u.z), x3 = h2f(u.w);
    float m0 = x0 + xr0 + ev.x;
    float m1 = x1 + xr1 + ev.y;
    float m2 = x2 + xr2 + ev.z;
    float m3 = x3 + xr3 + ev.w;
    float part =      m0 * (m0 > 0.f ? av.x : av2.x);
    part = fmaf(m1, (m1 > 0.f ? av.y : av2.y), part);
    part = fmaf(m2, (m2 > 0.f ? av.z : av2.z), part);
    part = fmaf(m3, (m3 > 0.f ? av.w : av2.w), part);
    part += __shfl_xor(part, 1);
    part += __shfl_xor(part, 2);
    part += __shfl_xor(part, 4);
    part += __shfl_xor(part, 8);
    float p = __expf(part);      // logits are O(0.2): softmax shift-invariant, no overflow
    den += p;
    ax = fmaf(p, x0, ax);
    ay = fmaf(p, x1, ay);
    az = fmaf(p, x2, az);
    aw = fmaf(p, x3, aw);
  };

  int beg = rowp[d], stop = rowp[d+1];
  int i = beg;
  for (; i + 2 <= stop; i += 2){
    int p0 = csrp[i], p1 = csrp[i+1];
    ushort4 u0 = *(const ushort4*)(xlr + ((size_t)(p0 & 0xFFFF) << 9) + cb);
    ushort4 u1 = *(const ushort4*)(xlr + ((size_t)(p1 & 0xFFFF) << 9) + cb);
    float4 ev0 = ld4(ep_l + (p0 >> 16)*HC + cb);
    float4 ev1 = ld4(ep_l + (p1 >> 16)*HC + cb);
    body(u0, ev0);
    body(u1, ev1);
  }
  if (i < stop){
    int p0 = csrp[i];
    ushort4 u0 = *(const ushort4*)(xlr + ((size_t)(p0 & 0xFFFF) << 9) + cb);
    float4 ev0 = ld4(ep_l + (p0 >> 16)*HC + cb);
    body(u0, ev0);
  }

  float inv = (den > 0.f) ? 1.f/den : 0.f;
  ax *= inv; ay *= inv; az *= inv; aw *= inv;

  ax += __shfl_xor(ax,16); ay += __shfl_xor(ay,16); az += __shfl_xor(az,16); aw += __shfl_xor(aw,16);
  ax += __shfl_xor(ax,32); ay += __shfl_xor(ay,32); az += __shfl_xor(az,32); aw += __shfl_xor(aw,32);

  int cc = (lane & 15) << 2;
  float4 bv = ld4(bias_l + cc);
  float h0 = ax*0.25f + bv.x;
  float h1 = ay*0.25f + bv.y;
  float h2 = az*0.25f + bv.z;
  float h3 = aw*0.25f + bv.w;

  float s1 = h0+h1+h2+h3;
  float s2 = h0*h0 + h1*h1 + h2*h2 + h3*h3;
  s1 += __shfl_xor(s1,1); s2 += __shfl_xor(s2,1);
  s1 += __shfl_xor(s1,2); s2 += __shfl_xor(s2,2);
  s1 += __shfl_xor(s1,4); s2 += __shfl_xor(s2,4);
  s1 += __shfl_xor(s1,8); s2 += __shfl_xor(s2,8);
  float mu  = s1 * (1.f/64.f);
  float var = fmaxf(s2*(1.f/64.f) - mu*mu, 0.f);
  float rstd = rsqrtf(var + 1e-5f);
  float4 gv  = ld4(g_l + cc);
  float4 bbv = ld4(b_l + cc);
  float r0 = (h0-mu)*rstd*gv.x + bbv.x;
  float r1 = (h1-mu)*rstd*gv.y + bbv.y;
  float r2 = (h2-mu)*rstd*gv.z + bbv.z;
  float r3 = (h3-mu)*rstd*gv.w + bbv.w;
  if (use_res){
    float4 hv = ld4(h_in + (size_t)d*HID + cc);
    r0 += hv.x; r1 += hv.y; r2 += hv.z; r3 += hv.w;
  }
  if (do_relu){
    r0 = fmaxf(r0, 0.f); r1 = fmaxf(r1, 0.f);
    r2 = fmaxf(r2, 0.f); r3 = fmaxf(r3, 0.f);
  }
  if (lane < 16){
    float4 o = {r0, r1, r2, r3};
    *(float4*)(h_out + (size_t)d*HID + cc) = o;
    ushort4 ob = {f2b(r0), f2b(r1), f2b(r2), f2b(r3)};
    *(ushort4*)(hbf + (size_t)d*HID + cc) = ob;
  }
}

// ---------------- launch ----------------
extern "C" void kernel_launch(void* const* d_in, const int* in_sizes, int n_in,
                              void* d_out, int out_size, void* d_ws, size_t ws_size,
                              hipStream_t stream){
  const float* x    = (const float*)d_in[0];
  const int*   ei   = (const int*)d_in[1];
  const int*   ea   = (const int*)d_in[2];
  const float* inW  = (const float*)d_in[3];
  const float* inb  = (const float*)d_in[4];
  const float* etab = (const float*)d_in[5];
  const float* Wl   = (const float*)d_in[6];
  const float* bl   = (const float*)d_in[7];
  const float* Wr   = (const float*)d_in[8];
  const float* br   = (const float*)d_in[9];
  const float* We   = (const float*)d_in[10];
  const float* att  = (const float*)d_in[11];
  const float* ob   = (const float*)d_in[12];
  const float* lg   = (const float*)d_in[13];
  const float* lb   = (const float*)d_in[14];

  char* w = (char*)d_ws;
  size_t off = 0;
  auto alloc = [&](size_t bytes)->char*{
    char* p = w + off;
    off = (off + bytes + 255) & ~(size_t)255;
    return p;
  };
  float* hA    = (float*)alloc((size_t)NN*HID*4);
  float* hB    = (float*)alloc((size_t)NN*HID*4);
  unsigned short* hbf = (unsigned short*)alloc((size_t)NN*HID*2);
  unsigned short* xlr = (unsigned short*)alloc((size_t)NN*512*2);
  unsigned short* inW_bf = (unsigned short*)alloc((size_t)HID*INDIM*2);
  unsigned short* Wlr    = (unsigned short*)alloc((size_t)NL*512*HID*2);
  float* blr   = (float*)alloc((size_t)NL*512*4);
  float* ep    = (float*)alloc((size_t)NL*3*HC*4);
  int*   deg   = (int*)alloc((size_t)NN*4);
  int*   bsum  = (int*)alloc((size_t)SCAN_NB*4);
  int*   rowp  = (int*)alloc((size_t)(NN+1)*4);
  int*   csrp  = (int*)alloc((size_t)NE*4);

  hipMemsetAsync(deg, 0, (size_t)NN*4, stream);

  const int* srcp = ei;
  const int* dstp = ei + NE;
  deg_kernel<<<dim3((NE+255)/256), dim3(256), 0, stream>>>(dstp, deg);
  scanA_kernel<<<dim3(SCAN_NB), dim3(256), 0, stream>>>(deg, bsum);
  scanB_kernel<<<dim3(1), dim3(256), 0, stream>>>(bsum);
  scanC_kernel<<<dim3(SCAN_NB), dim3(256), 0, stream>>>(deg, bsum, rowp);
  scatter_kernel<<<dim3((NE+255)/256), dim3(256), 0, stream>>>(srcp, dstp, ea, rowp, deg, csrp);
  prep_kernel<<<dim3(64), dim3(256), 0, stream>>>(inW, Wl, Wr, bl, br, etab, We, inW_bf, Wlr, blr, ep);

  const int MB = (NN + 127)/128;   // 391
  gemm_in_kernel<<<dim3(MB), dim3(256), 0, stream>>>(x, inW_bf, inb, hA, hbf);

  float* hcur = hA; float* hnext = hB;
  for (int l=0; l<NL; l++){
    gemm_lr_kernel<<<dim3(MB,8), dim3(256), 0, stream>>>(
        hbf, Wlr + (size_t)l*512*HID, blr + (size_t)l*512, xlr);
    float* hout = (l == NL-1) ? (float*)d_out : hnext;
    agg_kernel<<<dim3((NN+3)/4), dim3(256), 0, stream>>>(
        xlr, rowp, csrp,
        ep + (size_t)l*3*HC, att + (size_t)l*HC,
        ob + (size_t)l*HID, lg + (size_t)l*HID, lb + (size_t)l*HID,
        hcur, hout, hbf, (l >= NL/2) ? 1 : 0, (l < NL-1) ? 1 : 0);
    float* t = hcur; hcur = hnext; hnext = t;
  }
}